// Round 1
// baseline (119.562 us; speedup 1.0000x reference)
//
#include <hip/hip_runtime.h>

// Problem constants (from reference): B=64, L=256, C_IN=5, KERNEL=4, C=8.
// S = L - (KERNEL-1) = 253 scan steps. Output per batch: 8+64+512+4096 = 4680.
#define L_IN      256
#define S_STEPS   253
#define CIN       5
#define WS_STRIDE 2048   // floats per batch in workspace (253*8=2024 used, +pad for prefetch)

// ---------------------------------------------------------------------------
// Kernel 1: conv-augment the path and emit per-step increments dx[b][t][0..7]
// into the workspace. One block per batch, one thread per time position.
// ---------------------------------------------------------------------------
__global__ __launch_bounds__(256) void aug_inc_kernel(
    const float* __restrict__ inp,
    const float* __restrict__ w1, const float* __restrict__ b1,
    const float* __restrict__ w2, const float* __restrict__ b2,
    const float* __restrict__ w3, const float* __restrict__ b3,
    float* __restrict__ dxg)
{
    const int b = blockIdx.x;      // batch
    const int t = threadIdx.x;     // time position 0..252 (253..255 idle)
    __shared__ float path[S_STEPS][8];

    if (t < S_STEPS) {
        const float* __restrict__ x = inp + b * (L_IN * CIN);
        // conv1: (8,5,4) VALID at position t  -> h1[o] = b1[o] + sum_{k,i} x[t+k,i]*w1[o,i,k]
        float h1[8];
        #pragma unroll
        for (int o = 0; o < 8; ++o) h1[o] = b1[o];
        #pragma unroll
        for (int kk = 0; kk < 4; ++kk) {
            #pragma unroll
            for (int ci = 0; ci < CIN; ++ci) {
                float v = x[(t + kk) * CIN + ci];
                #pragma unroll
                for (int o = 0; o < 8; ++o) h1[o] = fmaf(v, w1[o * 20 + ci * 4 + kk], h1[o]);
            }
        }
        // relu -> conv2 (8,8,1) -> relu -> conv3 (2,8,1)
        float r1[8];
        #pragma unroll
        for (int o = 0; o < 8; ++o) r1[o] = h1[o] > 0.f ? h1[o] : 0.f;
        float h2[8];
        #pragma unroll
        for (int o = 0; o < 8; ++o) h2[o] = b2[o];
        #pragma unroll
        for (int p = 0; p < 8; ++p) {
            #pragma unroll
            for (int o = 0; o < 8; ++o) h2[o] = fmaf(r1[p], w2[o * 8 + p], h2[o]);
        }
        float r2[8];
        #pragma unroll
        for (int o = 0; o < 8; ++o) r2[o] = h2[o] > 0.f ? h2[o] : 0.f;
        float h30 = b3[0], h31 = b3[1];
        #pragma unroll
        for (int p = 0; p < 8; ++p) {
            h30 = fmaf(r2[p], w3[p], h30);
            h31 = fmaf(r2[p], w3[8 + p], h31);
        }
        // augmented path row t: [orig(5) | time(1) | conv(2)]
        #pragma unroll
        for (int c = 0; c < 5; ++c) path[t][c] = x[(t + 3) * CIN + c];
        path[t][5] = (float)(t + 3) * (1.0f / 255.0f);
        path[t][6] = h30;
        path[t][7] = h31;
    }
    __syncthreads();
    if (t < S_STEPS) {
        float inc[8];
        #pragma unroll
        for (int c = 0; c < 8; ++c) {
            float prev = (t > 0) ? path[t - 1][c] : 0.f;
            inc[c] = path[t][c] - prev;
        }
        float4* dst = reinterpret_cast<float4*>(dxg + (size_t)b * WS_STRIDE + t * 8);
        dst[0] = make_float4(inc[0], inc[1], inc[2], inc[3]);
        dst[1] = make_float4(inc[4], inc[5], inc[6], inc[7]);
    }
}

// ---------------------------------------------------------------------------
// Kernel 2: the 253-step signature scan.
// Grid: 128 blocks (2 per batch) x 256 threads (4 waves).
//   wave -> tensor index i (wave-uniform => dx_i and dx[0..7] are scalar loads)
//   lane -> (j,k); registers hold l = 0..7 of s4[i][j][k][l].
// s1_i, s2[ij], s3[ijk] maintained redundantly per thread: no barriers, no LDS.
// ---------------------------------------------------------------------------
__global__ __launch_bounds__(256) void sig_kernel(
    const float* __restrict__ dxg, float* __restrict__ out)
{
    const int blk  = blockIdx.x;          // 0..127
    const int b    = blk >> 1;            // batch
    const int tid  = threadIdx.x;
    const int wave = tid >> 6;            // 0..3
    const int i    = ((blk & 1) << 2) | wave;  // 0..7
    const int lane = tid & 63;
    const int j    = lane >> 3;
    const int k    = lane & 7;
    const int iu   = __builtin_amdgcn_readfirstlane(i);  // force SGPR index

    const float* __restrict__ base = dxg + (size_t)b * WS_STRIDE;

    float s1 = 0.f, s2 = 0.f, s3 = 0.f;
    float s4[8];
    #pragma unroll
    for (int l = 0; l < 8; ++l) s4[l] = 0.f;

    // prefetch step 0
    float a_c = base[iu];   // uniform address -> s_load
    float b_c = base[j];    // divergent within 32B line -> one coalesced dword load
    float c_c = base[k];
    float d_c[8];
    #pragma unroll
    for (int l = 0; l < 8; ++l) d_c[l] = base[l];  // uniform -> s_load(x8)

    for (int t = 0; t < S_STEPS; ++t) {
        // prefetch next step (row 253 is in-bounds pad, never consumed)
        const float* nx = base + (t + 1) * 8;
        float a_n = nx[iu];
        float b_n = nx[j];
        float c_n = nx[k];
        float d_n[8];
        #pragma unroll
        for (int l = 0; l < 8; ++l) d_n[l] = nx[l];

        // rank-1 factored signature update (uses OLD s1,s2,s3)
        const float a = a_c, bb = b_c, cc = c_c;
        float t2    = fmaf(a, 0.5f, s1);                       // a/2 + s1
        float t3    = fmaf(s1, 0.5f, a * (1.f / 6.f));         // a/6 + s1/2
        float t4    = fmaf(s1, (1.f / 6.f), a * (1.f / 24.f)); // a/24 + s1/6
        float coef3 = fmaf(bb, t3, s2);
        float u     = fmaf(bb, t4, 0.5f * s2);
        float coef4 = fmaf(cc, u, s3);
        #pragma unroll
        for (int l = 0; l < 8; ++l) s4[l] = fmaf(coef4, d_c[l], s4[l]);
        s3 = fmaf(coef3, cc, s3);
        s2 = fmaf(t2, bb, s2);
        s1 += a;

        a_c = a_n; b_c = b_n; c_c = c_n;
        #pragma unroll
        for (int l = 0; l < 8; ++l) d_c[l] = d_n[l];
    }

    // epilogue: out[b] = [s1(8) | s2(64) | s3(512) | s4(4096)]
    float* __restrict__ ob = out + (size_t)b * 4680;
    if (lane == 0) ob[i] = s1;
    if (k == 0)    ob[8 + i * 8 + j] = s2;
    ob[72 + (i * 8 + j) * 8 + k] = s3;
    float4* o4 = reinterpret_cast<float4*>(ob + 584 + (size_t)((i * 8 + j) * 8 + k) * 8);
    o4[0] = make_float4(s4[0], s4[1], s4[2], s4[3]);
    o4[1] = make_float4(s4[4], s4[5], s4[6], s4[7]);
}

extern "C" void kernel_launch(void* const* d_in, const int* in_sizes, int n_in,
                              void* d_out, int out_size, void* d_ws, size_t ws_size,
                              hipStream_t stream)
{
    const float* inp = (const float*)d_in[0];
    const float* w1  = (const float*)d_in[1];
    const float* b1  = (const float*)d_in[2];
    const float* w2  = (const float*)d_in[3];
    const float* b2  = (const float*)d_in[4];
    const float* w3  = (const float*)d_in[5];
    const float* b3  = (const float*)d_in[6];
    float* out = (float*)d_out;
    float* dxg = (float*)d_ws;   // needs 64*2048*4 = 512 KiB

    aug_inc_kernel<<<64, 256, 0, stream>>>(inp, w1, b1, w2, b2, w3, b3, dxg);
    sig_kernel<<<128, 256, 0, stream>>>(dxg, out);
}

// Round 2
// 84.378 us; speedup vs baseline: 1.4170x; 1.4170x over previous
//
#include <hip/hip_runtime.h>

// B=64, L=256, C_IN=5, KERNEL=4, C=8. S = 253 real scan steps, padded to 256
// with zero increments (identity steps). Output per batch: 8+64+512+4096 = 4680.
#define L_IN    256
#define S_STEPS 253
#define CIN     5

__device__ __forceinline__ float readlane_f(float v, int lane) {
    return __int_as_float(__builtin_amdgcn_readlane(__float_as_int(v), lane));
}

// One kernel: phase 1 computes conv-augmented path increments into LDS,
// phase 2 runs the 256-step signature scan entirely out of LDS + registers.
// Grid: 128 blocks (2 per batch) x 256 threads (4 waves).
//   wave -> tensor index i (wave-uniform), lane -> (j,k), regs -> l of s4[ijkl].
// Per-iter LDS: 2x ds_read_b32 (dx[k] == c, dx[j] == b; same-address broadcast).
// Per-iter wave-uniform dx[0..7] and a=dx[i] come from v_readlane (VALU pipe).
__global__ __launch_bounds__(256) void fused_sig_kernel(
    const float* __restrict__ inp,
    const float* __restrict__ w1, const float* __restrict__ b1,
    const float* __restrict__ w2, const float* __restrict__ b2,
    const float* __restrict__ w3, const float* __restrict__ b3,
    float* __restrict__ out)
{
    const int blk = blockIdx.x;     // 0..127
    const int b   = blk >> 1;       // batch
    const int tid = threadIdx.x;

    __shared__ float path[S_STEPS][8];
    // rows 0..252: increments; 253..255: zeros (identity steps); 256..263: prefetch slop
    __shared__ float dxs[264][8];

    // ---------------- phase 1: conv augment -> path ----------------
    const int t = tid;
    if (t < S_STEPS) {
        const float* __restrict__ x = inp + b * (L_IN * CIN);
        float h1[8];
        #pragma unroll
        for (int o = 0; o < 8; ++o) h1[o] = b1[o];
        #pragma unroll
        for (int kk = 0; kk < 4; ++kk) {
            #pragma unroll
            for (int ci = 0; ci < CIN; ++ci) {
                float v = x[(t + kk) * CIN + ci];
                #pragma unroll
                for (int o = 0; o < 8; ++o) h1[o] = fmaf(v, w1[o * 20 + ci * 4 + kk], h1[o]);
            }
        }
        float r1[8];
        #pragma unroll
        for (int o = 0; o < 8; ++o) r1[o] = h1[o] > 0.f ? h1[o] : 0.f;
        float h2[8];
        #pragma unroll
        for (int o = 0; o < 8; ++o) h2[o] = b2[o];
        #pragma unroll
        for (int p = 0; p < 8; ++p) {
            #pragma unroll
            for (int o = 0; o < 8; ++o) h2[o] = fmaf(r1[p], w2[o * 8 + p], h2[o]);
        }
        float r2[8];
        #pragma unroll
        for (int o = 0; o < 8; ++o) r2[o] = h2[o] > 0.f ? h2[o] : 0.f;
        float h30 = b3[0], h31 = b3[1];
        #pragma unroll
        for (int p = 0; p < 8; ++p) {
            h30 = fmaf(r2[p], w3[p], h30);
            h31 = fmaf(r2[p], w3[8 + p], h31);
        }
        #pragma unroll
        for (int c = 0; c < 5; ++c) path[t][c] = x[(t + 3) * CIN + c];
        path[t][5] = (float)(t + 3) * (1.0f / 255.0f);
        path[t][6] = h30;
        path[t][7] = h31;
    }
    __syncthreads();
    // increments into dxs
    if (t < S_STEPS) {
        #pragma unroll
        for (int c = 0; c < 8; ++c) {
            float prev = (t > 0) ? path[t - 1][c] : 0.f;
            dxs[t][c] = path[t][c] - prev;
        }
    }
    if (tid < 88) {   // zero rows 253..263 (11 rows x 8)
        dxs[S_STEPS + (tid >> 3)][tid & 7] = 0.f;
    }
    __syncthreads();

    // ---------------- phase 2: signature scan ----------------
    const int wave  = __builtin_amdgcn_readfirstlane(tid >> 6);   // 0..3
    const int i     = ((blk & 1) << 2) | wave;                    // 0..7
    const int lane  = tid & 63;
    const int j     = lane >> 3;
    const int k     = lane & 7;
    const int ilane = i * 9;   // lane whose k == i (wave-uniform SGPR)

    float s1 = 0.f, s2 = 0.f, s3 = 0.f;
    float s4[8];
    #pragma unroll
    for (int l = 0; l < 8; ++l) s4[l] = 0.f;

    // depth-4 register pipeline over LDS reads
    float ownp[4], bbp[4];
    #pragma unroll
    for (int u = 0; u < 4; ++u) { ownp[u] = dxs[u][k]; bbp[u] = dxs[u][j]; }

    for (int tb = 0; tb < 256; tb += 4) {
        #pragma unroll
        for (int u = 0; u < 4; ++u) {
            const int tc = tb + u;
            // prefetch 4 ahead (rows <= 259, in-bounds; pad rows are zero/garbage-safe)
            float own_n = dxs[tc + 4][k];
            float bb_n  = dxs[tc + 4][j];

            const float own = ownp[u];        // dx[k] == cc
            const float bb  = bbp[u];         // dx[j]
            const float a   = readlane_f(own, ilane);   // dx[i], wave-uniform
            const float d0  = readlane_f(own, 0);
            const float d1  = readlane_f(own, 9);
            const float d2  = readlane_f(own, 18);
            const float d3  = readlane_f(own, 27);
            const float d4  = readlane_f(own, 36);
            const float d5  = readlane_f(own, 45);
            const float d6  = readlane_f(own, 54);
            const float d7  = readlane_f(own, 63);

            // rank-1 factored update (uses OLD s1,s2,s3)
            const float t2    = fmaf(a, 0.5f, s1);
            const float a6    = a * (1.0f / 6.0f);
            const float a24   = a * (1.0f / 24.0f);
            const float t3    = fmaf(s1, 0.5f, a6);
            const float t4    = fmaf(s1, (1.0f / 6.0f), a24);
            const float coef3 = fmaf(bb, t3, s2);
            const float hs2   = 0.5f * s2;
            const float uu    = fmaf(bb, t4, hs2);
            const float coef4 = fmaf(own, uu, s3);   // own == cc
            s4[0] = fmaf(coef4, d0, s4[0]);
            s4[1] = fmaf(coef4, d1, s4[1]);
            s4[2] = fmaf(coef4, d2, s4[2]);
            s4[3] = fmaf(coef4, d3, s4[3]);
            s4[4] = fmaf(coef4, d4, s4[4]);
            s4[5] = fmaf(coef4, d5, s4[5]);
            s4[6] = fmaf(coef4, d6, s4[6]);
            s4[7] = fmaf(coef4, d7, s4[7]);
            s3 = fmaf(coef3, own, s3);
            s2 = fmaf(t2, bb, s2);
            s1 += a;

            ownp[u] = own_n;
            bbp[u]  = bb_n;
        }
    }

    // ---------------- epilogue ----------------
    float* __restrict__ ob = out + (size_t)b * 4680;
    if (lane == 0) ob[i] = s1;
    if (k == 0)    ob[8 + i * 8 + j] = s2;
    ob[72 + (i * 8 + j) * 8 + k] = s3;
    float4* o4 = reinterpret_cast<float4*>(ob + 584 + (size_t)((i * 8 + j) * 8 + k) * 8);
    o4[0] = make_float4(s4[0], s4[1], s4[2], s4[3]);
    o4[1] = make_float4(s4[4], s4[5], s4[6], s4[7]);
}

extern "C" void kernel_launch(void* const* d_in, const int* in_sizes, int n_in,
                              void* d_out, int out_size, void* d_ws, size_t ws_size,
                              hipStream_t stream)
{
    const float* inp = (const float*)d_in[0];
    const float* w1  = (const float*)d_in[1];
    const float* b1  = (const float*)d_in[2];
    const float* w2  = (const float*)d_in[3];
    const float* b2  = (const float*)d_in[4];
    const float* w3  = (const float*)d_in[5];
    const float* b3  = (const float*)d_in[6];
    float* out = (float*)d_out;

    fused_sig_kernel<<<128, 256, 0, stream>>>(inp, w1, b1, w2, b2, w3, b3, out);
}

// Round 3
// 83.449 us; speedup vs baseline: 1.4328x; 1.0111x over previous
//
#include <hip/hip_runtime.h>

// B=64, L=256, C_IN=5, KERNEL=4, C=8. S = 253 real scan steps, padded to 256
// with zero increments (identity steps). Output per batch: 8+64+512+4096 = 4680.
#define L_IN    256
#define S_STEPS 253
#define CIN     5

// One kernel: phase 1 computes conv-augmented path increments into LDS,
// phase 2 runs the 256-step signature scan entirely out of LDS + registers.
// Grid: 128 blocks (2 per batch) x 256 threads (4 waves).
//   wave -> tensor index i (wave-uniform), lane -> (j,k), regs -> l of s4[ijkl].
// Per-iter LDS (all hazard-free, no readlane):
//   3x ds_read_b32  (a = dx[i] broadcast, own = dx[k], bb = dx[j])
//   2x ds_read_b128 (row dx[0..7] broadcast -> VGPR operands for the s4 FMAs)
__global__ __launch_bounds__(256) void fused_sig_kernel(
    const float* __restrict__ inp,
    const float* __restrict__ w1, const float* __restrict__ b1,
    const float* __restrict__ w2, const float* __restrict__ b2,
    const float* __restrict__ w3, const float* __restrict__ b3,
    float* __restrict__ out)
{
    const int blk = blockIdx.x;     // 0..127
    const int b   = blk >> 1;       // batch
    const int tid = threadIdx.x;

    __shared__ float path[S_STEPS][8];
    // rows 0..252: increments; 253..255: zeros (identity steps); 256..263: prefetch slop
    __shared__ __align__(16) float dxs[264][8];

    // ---------------- phase 1: conv augment -> path ----------------
    const int t = tid;
    if (t < S_STEPS) {
        const float* __restrict__ x = inp + b * (L_IN * CIN);
        float h1[8];
        #pragma unroll
        for (int o = 0; o < 8; ++o) h1[o] = b1[o];
        #pragma unroll
        for (int kk = 0; kk < 4; ++kk) {
            #pragma unroll
            for (int ci = 0; ci < CIN; ++ci) {
                float v = x[(t + kk) * CIN + ci];
                #pragma unroll
                for (int o = 0; o < 8; ++o) h1[o] = fmaf(v, w1[o * 20 + ci * 4 + kk], h1[o]);
            }
        }
        float r1[8];
        #pragma unroll
        for (int o = 0; o < 8; ++o) r1[o] = h1[o] > 0.f ? h1[o] : 0.f;
        float h2[8];
        #pragma unroll
        for (int o = 0; o < 8; ++o) h2[o] = b2[o];
        #pragma unroll
        for (int p = 0; p < 8; ++p) {
            #pragma unroll
            for (int o = 0; o < 8; ++o) h2[o] = fmaf(r1[p], w2[o * 8 + p], h2[o]);
        }
        float r2[8];
        #pragma unroll
        for (int o = 0; o < 8; ++o) r2[o] = h2[o] > 0.f ? h2[o] : 0.f;
        float h30 = b3[0], h31 = b3[1];
        #pragma unroll
        for (int p = 0; p < 8; ++p) {
            h30 = fmaf(r2[p], w3[p], h30);
            h31 = fmaf(r2[p], w3[8 + p], h31);
        }
        #pragma unroll
        for (int c = 0; c < 5; ++c) path[t][c] = x[(t + 3) * CIN + c];
        path[t][5] = (float)(t + 3) * (1.0f / 255.0f);
        path[t][6] = h30;
        path[t][7] = h31;
    }
    if (tid < 88) {   // zero pad rows 253..263 (11 rows x 8)
        dxs[S_STEPS + (tid >> 3)][tid & 7] = 0.f;
    }
    __syncthreads();
    if (t < S_STEPS) {
        #pragma unroll
        for (int c = 0; c < 8; ++c) {
            float prev = (t > 0) ? path[t - 1][c] : 0.f;
            dxs[t][c] = path[t][c] - prev;
        }
    }
    __syncthreads();

    // ---------------- phase 2: signature scan ----------------
    const int wave = __builtin_amdgcn_readfirstlane(tid >> 6);   // 0..3
    const int i    = ((blk & 1) << 2) | wave;                    // 0..7, wave-uniform
    const int lane = tid & 63;
    const int j    = lane >> 3;
    const int k    = lane & 7;

    float s1 = 0.f, s2 = 0.f, s3 = 0.f;
    float s4[8];
    #pragma unroll
    for (int l = 0; l < 8; ++l) s4[l] = 0.f;

    const float4* __restrict__ dx4 = reinterpret_cast<const float4*>(&dxs[0][0]);

    // depth-4 register pipeline over LDS reads
    float a_p[4], own_p[4], bb_p[4];
    float4 r0_p[4], r1_p[4];
    #pragma unroll
    for (int u = 0; u < 4; ++u) {
        a_p[u]   = dxs[u][i];
        own_p[u] = dxs[u][k];
        bb_p[u]  = dxs[u][j];
        r0_p[u]  = dx4[u * 2];
        r1_p[u]  = dx4[u * 2 + 1];
    }

    for (int tb = 0; tb < 256; tb += 4) {
        #pragma unroll
        for (int u = 0; u < 4; ++u) {
            const int tn = tb + u + 4;   // prefetch row (<= 259, in-bounds pad)
            float  a_n   = dxs[tn][i];
            float  own_n = dxs[tn][k];
            float  bb_n  = dxs[tn][j];
            float4 r0_n  = dx4[tn * 2];
            float4 r1_n  = dx4[tn * 2 + 1];

            const float a   = a_p[u];     // dx[i]
            const float own = own_p[u];   // dx[k] == cc
            const float bb  = bb_p[u];    // dx[j]
            const float4 r0 = r0_p[u];    // dx[0..3]
            const float4 r1 = r1_p[u];    // dx[4..7]

            // rank-1 factored update (uses OLD s1,s2,s3)
            const float t2    = fmaf(a, 0.5f, s1);
            const float t3    = fmaf(s1, 0.5f, a * (1.0f / 6.0f));
            const float t4    = fmaf(s1, (1.0f / 6.0f), a * (1.0f / 24.0f));
            const float coef3 = fmaf(bb, t3, s2);
            const float uu    = fmaf(bb, t4, 0.5f * s2);
            const float coef4 = fmaf(own, uu, s3);   // own == cc
            s4[0] = fmaf(coef4, r0.x, s4[0]);
            s4[1] = fmaf(coef4, r0.y, s4[1]);
            s4[2] = fmaf(coef4, r0.z, s4[2]);
            s4[3] = fmaf(coef4, r0.w, s4[3]);
            s4[4] = fmaf(coef4, r1.x, s4[4]);
            s4[5] = fmaf(coef4, r1.y, s4[5]);
            s4[6] = fmaf(coef4, r1.z, s4[6]);
            s4[7] = fmaf(coef4, r1.w, s4[7]);
            s3 = fmaf(coef3, own, s3);
            s2 = fmaf(t2, bb, s2);
            s1 += a;

            a_p[u] = a_n; own_p[u] = own_n; bb_p[u] = bb_n;
            r0_p[u] = r0_n; r1_p[u] = r1_n;
        }
    }

    // ---------------- epilogue ----------------
    float* __restrict__ ob = out + (size_t)b * 4680;
    if (lane == 0) ob[i] = s1;
    if (k == 0)    ob[8 + i * 8 + j] = s2;
    ob[72 + (i * 8 + j) * 8 + k] = s3;
    float4* o4 = reinterpret_cast<float4*>(ob + 584 + (size_t)((i * 8 + j) * 8 + k) * 8);
    o4[0] = make_float4(s4[0], s4[1], s4[2], s4[3]);
    o4[1] = make_float4(s4[4], s4[5], s4[6], s4[7]);
}

extern "C" void kernel_launch(void* const* d_in, const int* in_sizes, int n_in,
                              void* d_out, int out_size, void* d_ws, size_t ws_size,
                              hipStream_t stream)
{
    const float* inp = (const float*)d_in[0];
    const float* w1  = (const float*)d_in[1];
    const float* b1  = (const float*)d_in[2];
    const float* w2  = (const float*)d_in[3];
    const float* b2  = (const float*)d_in[4];
    const float* w3  = (const float*)d_in[5];
    const float* b3  = (const float*)d_in[6];
    float* out = (float*)d_out;

    fused_sig_kernel<<<128, 256, 0, stream>>>(inp, w1, b1, w2, b2, w3, b3, out);
}